// Round 10
// baseline (347.407 us; speedup 1.0000x reference)
//
#include <hip/hip_runtime.h>
#include <hip/hip_fp16.h>

// GRU (reset_after, inference) fused with dense head — MFMA, 2-phase split.
// B=1024 rows, T=512 steps, F=16, H=64. 64 blocks x 512 threads (8 waves).
// R9 post-mortem: MFMA pipe ~134 cy/step, VALU ~460, stall ~650 of 1242 —
// everything serialized at 1 wave/SIMD. Fix: split the step across 2 waves
// per unit-group (2 waves/SIMD, complementary busy windows):
//   ZR-wave g (wid=g<4):  cz,cr (6 MFMAs, x-part first) -> z,r = sigm ->
//                         write zrz/zrr[g][lane] (same-lane layout handoff)
//   H-wave g (wid=g+4):   crh,cxh (3 MFMAs) concurrently; after B1: read
//                         z,r -> tanh -> h-update -> publish h (fp16)
// Two barriers/step: B1 (zr handoff), B2 (h publish). No dbuf needed for
// zr (write<B1, read<B2, next write>B2). hs double-buffered on t-parity.
// Biases bz,br,bxh folded into MFMA via x-chunk row16 (A[.,16]=1, B row16 =
// bias); brh via crh C-init. A/B/C layouts as verified in R9 (absmax 9.77e-4).

#define T_ 512
#define F_ 16
#define H_ 64
#define ROWS_ 16
#define HSS 80   // hs row stride in fp16 (160 B, 16-B aligned for b128)

typedef _Float16 half_t;
typedef _Float16 h8 __attribute__((ext_vector_type(8)));
typedef float f32x4 __attribute__((ext_vector_type(4)));

__device__ __forceinline__ float fast_rcp(float a) {
    return __builtin_amdgcn_rcpf(a);   // v_rcp_f32, ~1 ULP
}
__device__ __forceinline__ float sigm(float a) {
    return fast_rcp(1.0f + __expf(-a));
}
__device__ __forceinline__ float tanh_fast(float a) {
    // tanh(a) = 1 - 2/(exp(2a)+1); saturates correctly for large |a|
    return 1.0f - 2.0f * fast_rcp(__expf(2.0f * a) + 1.0f);
}

__global__ __launch_bounds__(512, 1) void gru_fused(
    const float* __restrict__ x, const float* __restrict__ W,
    const float* __restrict__ U, const float* __restrict__ b,
    const float* __restrict__ w1, const float* __restrict__ b1,
    const float* __restrict__ gamma_, const float* __restrict__ beta_,
    const float* __restrict__ mmean, const float* __restrict__ mvar,
    const float* __restrict__ w2, const float* __restrict__ b2,
    float* __restrict__ out)
{
    __shared__ __align__(16) half_t hs[2][ROWS_][HSS];   // 5 KB, dbuf on t
    __shared__ __align__(16) float  zrz[4][64][4];       // 4 KB: z handoff
    __shared__ __align__(16) float  zrr[4][64][4];       // 4 KB: r handoff
    __shared__ float hf[ROWS_][H_ + 4];                  // final h, fp32

    const int tid = threadIdx.x;
    const int wid = tid >> 6;          // 0..7
    const bool isH = (wid >= 4);       // wave-uniform role
    const int g   = wid & 3;           // unit group 0..3
    const int l   = tid & 63;
    const int c   = l & 15;            // A-row / C-col within tile
    const int q   = l >> 4;            // k-block selector
    const int r0  = blockIdx.x * ROWS_;
    const int col = 16 * g + c;        // this lane's output unit (0..63)

    // zero both h buffers (h0 = 0)
    for (int i = tid; i < 2 * ROWS_ * HSS; i += 512)
        ((half_t*)hs)[i] = (half_t)0.0f;

    // biases (b is [2,192]: b[0]=input bias, b[1]=recurrent bias)
    const float bz  = b[col]       + b[192 + col];   // bi_z + br_z
    const float br_ = b[64 + col]  + b[256 + col];   // bi_r + br_r
    const float bxh = b[128 + col];                  // bi_h (x-part)
    const float brh = b[320 + col];                  // br_h (rec-part)

    // ---- per-role B fragments (fp16). Lane l holds B[k=...][n=col]. ----
    // ZR: P-tile = z gate, Q-tile = r gate. H: P-tile = rh (U) / xh (x-chunk).
    h8 bu_p0, bu_p1, bu_q0, bu_q1, bw_p, bw_q;
    if (!isH) {
        #pragma unroll
        for (int i = 0; i < 8; ++i) {
            const int k = 8 * q + i;
            bu_p0[i] = (half_t)U[k * 192 + col];              // Uz chunk0
            bu_p1[i] = (half_t)U[(32 + k) * 192 + col];       // Uz chunk1
            bu_q0[i] = (half_t)U[k * 192 + 64 + col];         // Ur chunk0
            bu_q1[i] = (half_t)U[(32 + k) * 192 + 64 + col];  // Ur chunk1
            // x-chunk rows 0..15 = W, row 16 = bias (A has 1.0 there), rest 0
            bw_p[i] = (q < 2) ? (half_t)W[k * 192 + col]
                              : ((q == 2 && i == 0) ? (half_t)bz  : (half_t)0.0f);
            bw_q[i] = (q < 2) ? (half_t)W[k * 192 + 64 + col]
                              : ((q == 2 && i == 0) ? (half_t)br_ : (half_t)0.0f);
        }
    } else {
        #pragma unroll
        for (int i = 0; i < 8; ++i) {
            const int k = 8 * q + i;
            bu_p0[i] = (half_t)U[k * 192 + 128 + col];        // Uh chunk0
            bu_p1[i] = (half_t)U[(32 + k) * 192 + 128 + col]; // Uh chunk1
            bw_p[i] = (q < 2) ? (half_t)W[k * 192 + 128 + col]
                              : ((q == 2 && i == 0) ? (half_t)bxh : (half_t)0.0f);
            bu_q0[i] = (half_t)0.0f; bu_q1[i] = (half_t)0.0f; bw_q[i] = (half_t)0.0f;
        }
    }

    __syncthreads();   // hs zeroed

    float hold[4] = {0.f, 0.f, 0.f, 0.f};   // H-waves: h for rows 4q+i

    // x: lane reads row (r0+c), feats 8*(q&1)..+7 (q>=2 duplicates; their
    // A-values hit zero B rows except the patched 1.0 at k=16).
    const float* xrow = x + (size_t)(r0 + c) * (T_ * F_) + 8 * (q & 1);
    float4 xfa = *(const float4*)(xrow);
    float4 xfb = *(const float4*)(xrow + 4);

    for (int t = 0; t < T_; ++t) {
        const int nb = t & 1;

        // A x-fragment; patch lane q==2 elem0 to 1.0 (bias row)
        h8 ax;
        ax[0] = (half_t)xfa.x; ax[1] = (half_t)xfa.y;
        ax[2] = (half_t)xfa.z; ax[3] = (half_t)xfa.w;
        ax[4] = (half_t)xfb.x; ax[5] = (half_t)xfb.y;
        ax[6] = (half_t)xfb.z; ax[7] = (half_t)xfb.w;
        if (q == 2) ax[0] = (half_t)1.0f;

        // prefetch next step's x (in flight across the whole step)
        const int tn = (t + 1 < T_) ? (t + 1) : t;
        const float4 nxa = *(const float4*)(xrow + tn * F_);
        const float4 nxb = *(const float4*)(xrow + tn * F_ + 4);

        // A h-fragments: row c, k = 8q (+32)
        const half_t* hrow = &hs[nb][c][0];
        const h8 ah0 = *(const h8*)(hrow + 8 * q);
        const h8 ah1 = *(const h8*)(hrow + 32 + 8 * q);

        if (!isH) {
            // ---- ZR phase: 6 MFMAs (x-parts first: independent of ah) ----
            f32x4 cp = {0.f, 0.f, 0.f, 0.f};
            f32x4 cq = {0.f, 0.f, 0.f, 0.f};
            cp = __builtin_amdgcn_mfma_f32_16x16x32_f16(ax,  bw_p,  cp, 0, 0, 0);
            cq = __builtin_amdgcn_mfma_f32_16x16x32_f16(ax,  bw_q,  cq, 0, 0, 0);
            cp = __builtin_amdgcn_mfma_f32_16x16x32_f16(ah0, bu_p0, cp, 0, 0, 0);
            cq = __builtin_amdgcn_mfma_f32_16x16x32_f16(ah0, bu_q0, cq, 0, 0, 0);
            cp = __builtin_amdgcn_mfma_f32_16x16x32_f16(ah1, bu_p1, cp, 0, 0, 0);
            cq = __builtin_amdgcn_mfma_f32_16x16x32_f16(ah1, bu_q1, cq, 0, 0, 0);
            *(float4*)&zrz[g][l][0] =
                make_float4(sigm(cp[0]), sigm(cp[1]), sigm(cp[2]), sigm(cp[3]));
            *(float4*)&zrr[g][l][0] =
                make_float4(sigm(cq[0]), sigm(cq[1]), sigm(cq[2]), sigm(cq[3]));
        } else {
            // ---- H phase 1: crh (bias C-init) + cxh, 3 MFMAs ----
            f32x4 crh = {brh, brh, brh, brh};
            f32x4 cxh = {0.f, 0.f, 0.f, 0.f};
            cxh = __builtin_amdgcn_mfma_f32_16x16x32_f16(ax,  bw_p,  cxh, 0, 0, 0);
            crh = __builtin_amdgcn_mfma_f32_16x16x32_f16(ah0, bu_p0, crh, 0, 0, 0);
            crh = __builtin_amdgcn_mfma_f32_16x16x32_f16(ah1, bu_p1, crh, 0, 0, 0);

            __syncthreads();   // B1: z,r visible

            // ---- H phase 2: gates tail + publish ----
            const float4 zv = *(const float4*)&zrz[g][l][0];
            const float4 rv = *(const float4*)&zrr[g][l][0];
            half_t* wrp = &hs[nb ^ 1][0][0] + col;
            {
                const float hh0 = tanh_fast(fmaf(rv.x, crh[0], cxh[0]));
                const float hh1 = tanh_fast(fmaf(rv.y, crh[1], cxh[1]));
                const float hh2 = tanh_fast(fmaf(rv.z, crh[2], cxh[2]));
                const float hh3 = tanh_fast(fmaf(rv.w, crh[3], cxh[3]));
                hold[0] = fmaf(zv.x, hold[0] - hh0, hh0);
                hold[1] = fmaf(zv.y, hold[1] - hh1, hh1);
                hold[2] = fmaf(zv.z, hold[2] - hh2, hh2);
                hold[3] = fmaf(zv.w, hold[3] - hh3, hh3);
                wrp[(4 * q + 0) * HSS] = (half_t)hold[0];
                wrp[(4 * q + 1) * HSS] = (half_t)hold[1];
                wrp[(4 * q + 2) * HSS] = (half_t)hold[2];
                wrp[(4 * q + 3) * HSS] = (half_t)hold[3];
            }
        }
        if (!isH) __syncthreads();   // B1 for ZR-waves (idle through H tail)

        xfa = nxa; xfb = nxb;
        __syncthreads();             // B2: h published for step t+1
    }

    // ---- head: y = relu(h @ w1 + b1); BN(inference); out = y @ w2 + b2 ----
    if (isH) {
        #pragma unroll
        for (int i = 0; i < 4; ++i)
            hf[4 * q + i][col] = hold[i];
    }
    __syncthreads();
    if (!isH) {
        const int j = l;             // head unit 0..63; wave g -> rows 4g..4g+3
        float y0 = b1[j], y1 = y0, y2 = y0, y3 = y0;
        #pragma unroll 8
        for (int k = 0; k < H_; ++k) {
            const float wk = w1[k * 64 + j];
            y0 = fmaf(hf[4 * g + 0][k], wk, y0);
            y1 = fmaf(hf[4 * g + 1][k], wk, y1);
            y2 = fmaf(hf[4 * g + 2][k], wk, y2);
            y3 = fmaf(hf[4 * g + 3][k], wk, y3);
        }
        const float sc = rsqrtf(mvar[j] + 1e-3f) * gamma_[j];
        const float mm = mmean[j], bt = beta_[j], v2 = w2[j];
        float yy[4] = {y0, y1, y2, y3};
        #pragma unroll
        for (int ri = 0; ri < 4; ++ri) {
            float yv = fmaxf(yy[ri], 0.0f);
            yv = (yv - mm) * sc + bt;
            float acc = yv * v2;
            #pragma unroll
            for (int off = 32; off > 0; off >>= 1)
                acc += __shfl_down(acc, off, 64);
            if (l == 0) out[r0 + 4 * g + ri] = acc + b2[0];
        }
    }
}

extern "C" void kernel_launch(void* const* d_in, const int* in_sizes, int n_in,
                              void* d_out, int out_size, void* d_ws, size_t ws_size,
                              hipStream_t stream) {
    const float* x      = (const float*)d_in[0];
    const float* W      = (const float*)d_in[1];
    const float* U      = (const float*)d_in[2];
    const float* b      = (const float*)d_in[3];
    const float* w1     = (const float*)d_in[4];
    const float* b1     = (const float*)d_in[5];
    const float* gamma_ = (const float*)d_in[6];
    const float* beta_  = (const float*)d_in[7];
    const float* mmean  = (const float*)d_in[8];
    const float* mvar   = (const float*)d_in[9];
    const float* w2     = (const float*)d_in[10];
    const float* b2     = (const float*)d_in[11];
    float* out = (float*)d_out;

    const int B = in_sizes[0] / (T_ * F_);   // 1024
    gru_fused<<<B / ROWS_, 512, 0, stream>>>(x, W, U, b, w1, b1, gamma_, beta_,
                                             mmean, mvar, w2, b2, out);
}